// Round 17
// baseline (191.851 us; speedup 1.0000x reference)
//
#include <hip/hip_runtime.h>
#include <math.h>

#define NB    4
#define NSEQ  2048
#define DMODEL 512
#define NH    8
#define HDIM  64
#define STR   72   // attn LDS tile row stride (bf16 units): 144B rows, 16B-aligned
#define LOG2E 1.44269504088896f

typedef __attribute__((ext_vector_type(8))) short short8;
typedef __attribute__((ext_vector_type(4))) float f32x4;
typedef __attribute__((ext_vector_type(16))) float f32x16;
typedef __attribute__((ext_vector_type(2))) unsigned int uint2v;
#define MFMA16 __builtin_amdgcn_mfma_f32_16x16x32_bf16
#define MFMA32 __builtin_amdgcn_mfma_f32_32x32x16_bf16
#define EXP2F __builtin_amdgcn_exp2f

__device__ __forceinline__ unsigned short f2bf(float f) {
    union { float f; unsigned int u; } v; v.f = f;
    unsigned int u = v.u;
    unsigned int r = (u + 0x7FFFu + ((u >> 16) & 1u)) >> 16;   // RNE
    return (unsigned short)r;
}
__device__ __forceinline__ void async16(void* lds, const void* g) {
    __builtin_amdgcn_global_load_lds(
        (const __attribute__((address_space(1))) unsigned int*)g,
        (__attribute__((address_space(3))) unsigned int*)lds, 16, 0, 0);
}
// pack two f32 -> one u32 of 2x bf16 (RNE), single VALU op
__device__ __forceinline__ unsigned cvtpk(float lo, float hi) {
    unsigned r;
    asm("v_cvt_pk_bf16_f32 %0, %1, %2" : "=v"(r) : "v"(lo), "v"(hi));
    return r;
}
// exchange: a.hi-lanes <-> b.lo-lanes. After: a = {a.lo | b.lo}, b = {a.hi | b.hi}
__device__ __forceinline__ void pswap(unsigned& a, unsigned& b) {
    uint2v r = __builtin_amdgcn_permlane32_swap(a, b, false, false);
    a = r[0]; b = r[1];
}

// ---------------------------------------------------------------------------
// Fused prep: [0,16384) mask ballots; [16384,20480) x->bf16; [20480,21504) W^T.
// ---------------------------------------------------------------------------
__global__ __launch_bounds__(256) void prep_kernel(
    const float* __restrict__ adj, unsigned long long* __restrict__ Mb,
    const float* __restrict__ x, unsigned short* __restrict__ xhi,
    const float* __restrict__ Wq, const float* __restrict__ Wk,
    const float* __restrict__ Wv, const float* __restrict__ Wo,
    unsigned short* __restrict__ Wthi)
{
    __shared__ float tile[32][33];
    const int bid = blockIdx.x;
    if (bid < 16384) {
        // ---- mask: Mb[kt*2048+q] = ballot(adj[q][kt*64+lane] > 0.5) ----
        const int w    = bid * 4 + (threadIdx.x >> 6);
        const int lane = threadIdx.x & 63;
        const int q  = w >> 5;
        const int kt = w & 31;
        float a = adj[(size_t)q * NSEQ + kt * 64 + lane];
        unsigned long long m = __ballot(a > 0.5f);
        if (lane == 0) Mb[(size_t)kt * NSEQ + q] = m;
    } else if (bid < 20480) {
        // ---- x (fp32) -> bf16, 4 elems/thread ----
        const int gid = (bid - 16384) * 256 + threadIdx.x;
        float4 a = ((const float4*)x)[gid];
        ushort4 h4;
        h4.x = f2bf(a.x); h4.y = f2bf(a.y); h4.z = f2bf(a.z); h4.w = f2bf(a.w);
        ((ushort4*)xhi)[gid] = h4;
    } else {
        // ---- W[k][n] fp32 -> Wt[mat][n][k] bf16, 32x32 tile per block ----
        const int local = bid - 20480;
        const int m  = local >> 8;
        const int rem = local & 255;
        const int k0 = (rem & 15) * 32, n0 = (rem >> 4) * 32;
        const float* W = (m == 0) ? Wq : (m == 1) ? Wk : (m == 2) ? Wv : Wo;
        const int tx = threadIdx.x & 31, ty = threadIdx.x >> 5;
        #pragma unroll
        for (int i = 0; i < 4; ++i)
            tile[ty * 4 + i][tx] = W[(size_t)(k0 + ty * 4 + i) * DMODEL + n0 + tx];
        __syncthreads();
        const size_t base = ((size_t)m * DMODEL) * DMODEL;
        #pragma unroll
        for (int i = 0; i < 4; ++i) {
            float f = tile[tx][ty * 4 + i];
            size_t idx = base + (size_t)(n0 + ty * 4 + i) * DMODEL + k0 + tx;
            Wthi[idx] = f2bf(f);
        }
    }
}

// ---------------------------------------------------------------------------
// Plain bf16 MFMA GEMM K-loop: 128x128 tile, BK=32, XOR-swizzled LDS,
// global_load_lds staging.
// ---------------------------------------------------------------------------
__device__ __forceinline__ void gemm_k_loop(
    const unsigned short* __restrict__ Ah,
    const unsigned short* __restrict__ Bh,
    char* smem, f32x4 acc[4][4])
{
    const int t    = threadIdx.x;
    const int lane = t & 63;
    const int wid  = t >> 6;
    const int quad = lane >> 4, l16 = lane & 15;
    const int wm   = wid >> 1,  wn  = wid & 1;

    unsigned short* As_h = (unsigned short*)(smem);
    unsigned short* Bs_h = (unsigned short*)(smem + 8192);

    const int ci0 = t, ci1 = 256 + t;
    const int r0 = ci0 >> 2, r1 = ci1 >> 2;
    const int c0 = (ci0 & 3) ^ ((r0 >> 1) & 3);
    const int c1 = (ci1 & 3) ^ ((r1 >> 1) & 3);
    const char* gAh = (const char*)Ah;
    const char* gBh = (const char*)Bh;
    const int ca = quad ^ ((l16 >> 1) & 3);

    for (int k0 = 0; k0 < DMODEL; k0 += 32) {
        const int kb = k0 * 2;
        async16(As_h + ci0 * 8, gAh + r0 * 1024 + kb + c0 * 16);
        async16(As_h + ci1 * 8, gAh + r1 * 1024 + kb + c1 * 16);
        async16(Bs_h + ci0 * 8, gBh + r0 * 1024 + kb + c0 * 16);
        async16(Bs_h + ci1 * 8, gBh + r1 * 1024 + kb + c1 * 16);
        __syncthreads();

        short8 ah[4], bh[4];
        #pragma unroll
        for (int i = 0; i < 4; ++i) {
            const int Ra = wm * 64 + i * 16 + l16;
            ah[i] = *(const short8*)(As_h + Ra * 32 + ca * 8);
            const int Rb = wn * 64 + i * 16 + l16;
            bh[i] = *(const short8*)(Bs_h + Rb * 32 + ca * 8);
        }
        #pragma unroll
        for (int mi = 0; mi < 4; ++mi)
            #pragma unroll
            for (int ni = 0; ni < 4; ++ni)
                acc[mi][ni] = MFMA16(ah[mi], bh[ni], acc[mi][ni], 0, 0, 0);
        __syncthreads();
    }
}

// ---------------------------------------------------------------------------
// QKV projection (MFMA, bf16). Q: *(0.125*log2e); K: plain; V: transposed.
// XCD-aware block swizzle; launch_bounds (256,4).
// ---------------------------------------------------------------------------
__global__ __launch_bounds__(256, 4) void qkv_mfma_kernel(
    const unsigned short* __restrict__ xhi,
    const unsigned short* __restrict__ Wthi,
    const float* __restrict__ bq, const float* __restrict__ bk, const float* __restrict__ bv,
    unsigned short* __restrict__ Qhi,
    unsigned short* __restrict__ Khi,
    unsigned short* __restrict__ Vt)
{
    __shared__ __align__(16) char smem[33280];
    const int t    = threadIdx.x;
    const int lane = t & 63;
    const int wid  = t >> 6;
    const int quad = lane >> 4, l16 = lane & 15;
    const int wm   = wid >> 1,  wn  = wid & 1;

    // XCD swizzle (bijective, 768 blocks): xcd = f&7 owns rows xcd*8..+7, all panels
    const int f    = blockIdx.x + 64 * blockIdx.y;
    const int xcd  = f & 7;
    const int loc  = f >> 3;                 // 0..95
    const int row0 = (xcd * 8 + (loc & 7)) * 128;
    const int yb   = loc >> 3;               // 0..11
    const int mtx  = yb >> 2;
    const int col0 = (yb & 3) * 128;

    f32x4 acc[4][4];
    #pragma unroll
    for (int i = 0; i < 4; ++i)
        #pragma unroll
        for (int j = 0; j < 4; ++j) acc[i][j] = (f32x4){0.f, 0.f, 0.f, 0.f};

    const size_t wslot = (size_t)mtx * DMODEL * DMODEL;
    gemm_k_loop(xhi + (size_t)row0 * DMODEL,
                Wthi + wslot + (size_t)col0 * DMODEL, smem, acc);

    const float* bias = (mtx == 0) ? bq : (mtx == 1) ? bk : bv;
    float bcol[4];
    #pragma unroll
    for (int ni = 0; ni < 4; ++ni) bcol[ni] = bias[col0 + wn * 64 + ni * 16 + l16];
    const int h = (col0 + wn * 64) >> 6;

    if (mtx < 2) {
        const float scale = (mtx == 0) ? (0.125f * LOG2E) : 1.0f;
        unsigned short* hig = (mtx == 0) ? Qhi : Khi;
        #pragma unroll
        for (int mi = 0; mi < 4; ++mi) {
            #pragma unroll
            for (int reg = 0; reg < 4; ++reg) {
                const int r = row0 + wm * 64 + mi * 16 + quad * 4 + reg;
                const int b = r >> 11, n = r & 2047;
                const size_t rowbase = ((size_t)(b * NH + h) * NSEQ + n) * HDIM;
                #pragma unroll
                for (int ni = 0; ni < 4; ++ni)
                    hig[rowbase + ni * 16 + l16] =
                        f2bf((acc[mi][ni][reg] + bcol[ni]) * scale);
            }
        }
    } else {
        // V: bias + bf16, transpose 64x64 per wave through LDS (stride 65)
        unsigned short* vt = (unsigned short*)smem + (size_t)wid * 64 * 65;
        #pragma unroll
        for (int mi = 0; mi < 4; ++mi)
            #pragma unroll
            for (int ni = 0; ni < 4; ++ni)
                #pragma unroll
                for (int reg = 0; reg < 4; ++reg)
                    vt[(mi * 16 + quad * 4 + reg) * 65 + ni * 16 + l16] =
                        f2bf(acc[mi][ni][reg] + bcol[ni]);
        const int b   = row0 >> 11;
        const int n0g = (row0 & 2047) + wm * 64;
        const int bh  = b * NH + h;
        unsigned short* gdst = Vt + ((size_t)bh * HDIM + lane) * NSEQ + n0g;
        #pragma unroll
        for (int nb = 0; nb < 8; ++nb) {
            unsigned short v[8];
            #pragma unroll
            for (int j = 0; j < 8; ++j) v[j] = vt[(nb * 8 + j) * 65 + lane];
            uint4 u;
            u.x = (unsigned)v[0] | ((unsigned)v[1] << 16);
            u.y = (unsigned)v[2] | ((unsigned)v[3] << 16);
            u.z = (unsigned)v[4] | ((unsigned)v[5] << 16);
            u.w = (unsigned)v[6] | ((unsigned)v[7] << 16);
            *(uint4*)(gdst + nb * 8) = u;
        }
    }
}

// ---------------------------------------------------------------------------
// Output projection (MFMA): ctx(bf16) @ Wo^T + bo -> out fp32 [B,N,D]
// ---------------------------------------------------------------------------
__global__ __launch_bounds__(256, 4) void out_mfma_kernel(
    const unsigned short* __restrict__ chi,
    const unsigned short* __restrict__ Wthi,
    const float* __restrict__ bo, float* __restrict__ out)
{
    __shared__ __align__(16) char smem[16384];
    const int t    = threadIdx.x;
    const int lane = t & 63;
    const int wid  = t >> 6;
    const int quad = lane >> 4, l16 = lane & 15;
    const int wm   = wid >> 1,  wn  = wid & 1;

    const int f    = blockIdx.x + 64 * blockIdx.y;
    const int xcd  = f & 7;
    const int loc  = f >> 3;                 // 0..31
    const int row0 = (xcd * 8 + (loc & 7)) * 128;
    const int col0 = (loc >> 3) * 128;       // 0..3

    f32x4 acc[4][4];
    #pragma unroll
    for (int i = 0; i < 4; ++i)
        #pragma unroll
        for (int j = 0; j < 4; ++j) acc[i][j] = (f32x4){0.f, 0.f, 0.f, 0.f};

    const size_t wslot = (size_t)3 * DMODEL * DMODEL;   // Wo
    gemm_k_loop(chi + (size_t)row0 * DMODEL,
                Wthi + wslot + (size_t)col0 * DMODEL, smem, acc);

    float bcol[4];
    #pragma unroll
    for (int ni = 0; ni < 4; ++ni) bcol[ni] = bo[col0 + wn * 64 + ni * 16 + l16];
    #pragma unroll
    for (int mi = 0; mi < 4; ++mi)
        #pragma unroll
        for (int reg = 0; reg < 4; ++reg) {
            const int r = row0 + wm * 64 + mi * 16 + quad * 4 + reg;
            float* orow = out + (size_t)r * DMODEL + col0 + wn * 64 + l16;
            #pragma unroll
            for (int ni = 0; ni < 4; ++ni)
                orow[ni * 16] = acc[mi][ni][reg] + bcol[ni];
        }
}

// ---------------------------------------------------------------------------
// MFMA flash attention, 32x32x16, runtime K-SPLIT (2 or 4). Verified R12 body;
// v17: grid z is HALVED per launch with a zoff so attn runs as two ~27 us
// dispatches — lowers the top-5 profiler visibility threshold from ~52 us to
// ~27 us so the non-attn kernels become observable. Decode unchanged (flat is
// partitioned exactly).
// ---------------------------------------------------------------------------
__global__ __launch_bounds__(256, 4) void attn_kernel(
    const unsigned short* __restrict__ Qhi,
    const unsigned short* __restrict__ Khi,
    const unsigned short* __restrict__ Vt,
    const unsigned long long* __restrict__ Mb,
    unsigned short* __restrict__ Opart, float* __restrict__ lpart,
    const int split, const int sshift, const int zoff)
{
    __shared__ __align__(16) unsigned short KS[64 * STR];   // 9.2 KB
    __shared__ __align__(16) unsigned short VS[64 * STR];   // 9.2 KB
    __shared__ unsigned long long mlut[16];                 // nibble -> bf16 mask

    const int t    = threadIdx.x;
    const int wq   = t >> 6;        // wave 0..3
    const int lane = t & 63;
    const int l32  = lane & 31;
    const int hw   = lane >> 5;     // half-wave

    // XCD swizzle (bijective): flat = x + 16y + 128z; xcd = flat&7.
    const int flat = blockIdx.x + 16 * (blockIdx.y + 8 * (blockIdx.z + zoff));
    const int xcd  = flat & 7;
    const int u    = flat >> 3;
    const int zi   = xcd * (split >> 1) + (u >> 7);
    const int h    = u & 7;
    const int qt   = (u >> 3) & 15;
    const int b    = zi >> sshift;
    const int ks   = zi & (split - 1);
    const int ktSpan = 32 >> sshift;
    const int bh   = b * NH + h;
    const int qa   = qt * 128 + wq * 32;

    // ---- init mask LUT: mlut[n] halfword j = (n>>j)&1 ? 0xFFFF : 0 ----
    if (t < 16) {
        unsigned long long m = 0;
        if (t & 1) m |= 0xFFFFull;
        if (t & 2) m |= 0xFFFF0000ull;
        if (t & 4) m |= 0xFFFFull << 32;
        if (t & 8) m |= 0xFFFFull << 48;
        mlut[t] = m;
    }

    // Q B-frags: row = qa+l32, k-chunk s*16 + hw*8 (scaled 0.125*log2e at proj)
    short8 qh[4];
    #pragma unroll
    for (int s = 0; s < 4; ++s)
        qh[s] = *(const short8*)(Qhi + ((size_t)bh * NSEQ + qa + l32) * HDIM + s * 16 + hw * 8);
    const unsigned long long* mrow = Mb + (qa + l32);

    short8 onesf;
    #pragma unroll
    for (int i = 0; i < 8; ++i) onesf[i] = (short)0x3F80;   // bf16 1.0

    f32x16 O0, O1, Ol;
    #pragma unroll
    for (int i = 0; i < 16; ++i) { O0[i] = 0.f; O1[i] = 0.f; Ol[i] = 0.f; }

    const unsigned short* gk = Khi + (size_t)bh * NSEQ * HDIM;
    const unsigned short* gv = Vt  + (size_t)bh * HDIM * NSEQ;

    const int ci0 = t, ci1 = t + 256;
    const int sr0 = ci0 >> 3, sc0 = (ci0 & 7) * 8;
    const int sr1 = ci1 >> 3, sc1 = (ci1 & 7) * 8;

    const int ktBeg = ks * ktSpan, ktEnd = ktBeg + ktSpan;

    // ---- prologue: stage first K/V tile ----
    {
        const int k0 = ktBeg * 64;
        uint4 ka = *(const uint4*)(gk + (size_t)(k0 + sr0) * HDIM + sc0);
        uint4 kc = *(const uint4*)(gk + (size_t)(k0 + sr1) * HDIM + sc1);
        uint4 va = *(const uint4*)(gv + (size_t)sr0 * NSEQ + k0 + sc0);
        uint4 vc = *(const uint4*)(gv + (size_t)sr1 * NSEQ + k0 + sc1);
        *(uint4*)&KS[sr0 * STR + sc0] = ka;
        *(uint4*)&KS[sr1 * STR + sc1] = kc;
        *(uint4*)&VS[sr0 * STR + sc0] = va;
        *(uint4*)&VS[sr1 * STR + sc1] = vc;
    }
    __syncthreads();   // fences both staging and mlut init

    for (int kt = ktBeg; kt < ktEnd; ++kt) {
        const unsigned short* ksrc = KS;
        const unsigned short* vsrc = VS;
        const unsigned long long mw = mrow[(size_t)kt * NSEQ];

        // ---- S^T = K Q^T per 32-key tile; exp2; in-register redistribute ----
        short8 pf[4];
        #pragma unroll
        for (int nt = 0; nt < 2; ++nt) {
            f32x16 S;
            #pragma unroll
            for (int i = 0; i < 16; ++i) S[i] = 0.f;
            __builtin_amdgcn_s_setprio(1);
            #pragma unroll
            for (int s = 0; s < 4; ++s) {
                short8 kb = *(const short8*)&ksrc[(nt * 32 + l32) * STR + s * 16 + hw * 8];
                S = MFMA32(kb, qh[s], S, 0, 0, 0);   // swapped: lane l32 = q col
            }
            __builtin_amdgcn_s_setprio(0);
            // lane (l32,hw): p[r] = P[q=qa+l32][key = nt*32 + (r&3)+8*(r>>2)+4*hw]
            float p[16];
            #pragma unroll
            for (int r = 0; r < 16; ++r) p[r] = EXP2F(S[r]);
            unsigned w[8];
            #pragma unroll
            for (int i = 0; i < 8; ++i) w[i] = cvtpk(p[2 * i], p[2 * i + 1]);
            // exchange half-wave partners: one swap fills two fragment words
            pswap(w[0], w[2]); pswap(w[1], w[3]);
            pswap(w[4], w[6]); pswap(w[5], w[7]);
            union { short8 s8; unsigned u[4]; } A, B2;
            A.u[0] = w[0]; A.u[1] = w[1]; A.u[2] = w[2]; A.u[3] = w[3];
            B2.u[0] = w[4]; B2.u[1] = w[5]; B2.u[2] = w[6]; B2.u[3] = w[7];
            pf[2 * nt]     = A.s8;    // keys nt*32 + hw*8 + 0..7 (per 16-chunk)
            pf[2 * nt + 1] = B2.s8;
        }

        // ---- issue next-tile global loads (latency hides under mask+PV) ----
        uint4 nk0, nk1, nv0, nv1;
        const bool more = (kt + 1 < ktEnd);
        if (more) {
            const int k0n = (kt + 1) * 64;
            nk0 = *(const uint4*)(gk + (size_t)(k0n + sr0) * HDIM + sc0);
            nk1 = *(const uint4*)(gk + (size_t)(k0n + sr1) * HDIM + sc1);
            nv0 = *(const uint4*)(gv + (size_t)sr0 * NSEQ + k0n + sc0);
            nv1 = *(const uint4*)(gv + (size_t)sr1 * NSEQ + k0n + sc1);
        }

        // ---- apply adjacency mask via LDS nibble LUT ----
        #pragma unroll
        for (int s = 0; s < 4; ++s) {
            const unsigned bits8 = (unsigned)(mw >> (s * 16 + hw * 8)) & 0xFFu;
            const unsigned long long lo = mlut[bits8 & 15u];
            const unsigned long long hi = mlut[bits8 >> 4];
            union { short8 s8; uint4 u; } x; x.s8 = pf[s];
            x.u.x &= (unsigned)lo; x.u.y &= (unsigned)(lo >> 32);
            x.u.z &= (unsigned)hi; x.u.w &= (unsigned)(hi >> 32);
            pf[s] = x.s8;
        }

        // ---- O += P @ V ; l += P @ ones ----
        __builtin_amdgcn_s_setprio(1);
        #pragma unroll
        for (int s = 0; s < 4; ++s) {
            short8 v0 = *(const short8*)&vsrc[(l32) * STR + s * 16 + hw * 8];
            short8 v1 = *(const short8*)&vsrc[(32 + l32) * STR + s * 16 + hw * 8];
            O0 = MFMA32(pf[s], v0, O0, 0, 0, 0);
            O1 = MFMA32(pf[s], v1, O1, 0, 0, 0);
            Ol = MFMA32(pf[s], onesf, Ol, 0, 0, 0);
        }
        __builtin_amdgcn_s_setprio(0);

        // ---- barrier 1: all waves done READING KS/VS for this tile ----
        __syncthreads();
        // ---- write staged regs into the (single) buffer ----
        if (more) {
            *(uint4*)&KS[sr0 * STR + sc0] = nk0;
            *(uint4*)&KS[sr1 * STR + sc1] = nk1;
            *(uint4*)&VS[sr0 * STR + sc0] = nv0;
            *(uint4*)&VS[sr1 * STR + sc1] = nv1;
        }
        // ---- barrier 2: writes visible for next iteration ----
        __syncthreads();
    }

    // ---- write bf16 O-partials (no normalization; merge kernel sums) ----
    const size_t obase = ((size_t)(ks * NB + b) * NH + h) * NSEQ;
    #pragma unroll
    for (int r = 0; r < 16; ++r) {
        const int qrow = qa + (r & 3) + 8 * (r >> 2) + 4 * hw;
        unsigned short* orow = Opart + (obase + qrow) * HDIM;
        orow[l32]      = f2bf(O0[r]);
        orow[32 + l32] = f2bf(O1[r]);
        if (l32 == 0) lpart[obase + qrow] = Ol[r];
    }
}

// ---------------------------------------------------------------------------
// Merge: ctx = (sum_i O_i) / (sum_i l_i), bf16 partials -> chi [B,N,D]
// ---------------------------------------------------------------------------
__global__ __launch_bounds__(256) void merge_kernel(
    const unsigned short* __restrict__ Opart, const float* __restrict__ lpart,
    unsigned short* __restrict__ chi, const int split)
{
    const int g = blockIdx.x * 256 + threadIdx.x;   // 262144 threads
    const int qitem = g >> 2;                       // (b*NH+h)*NSEQ+n
    const int grp = g & 3;                          // 16-dim group
    const size_t QS = (size_t)NB * NH * NSEQ;
    const size_t HS = QS * HDIM;

    float lsum = 0.f;
    for (int i = 0; i < split; ++i) lsum += lpart[qitem + (size_t)i * QS];
    const float inv = 1.0f / lsum;

    float acc[16];
    #pragma unroll
    for (int j = 0; j < 16; ++j) acc[j] = 0.f;
    const unsigned short* pa = Opart + (size_t)qitem * HDIM + grp * 16;
    for (int i = 0; i < split; ++i) {
        const unsigned short* p = pa + (size_t)i * HS;
        uint4 v0 = *(const uint4*)(p);
        uint4 v1 = *(const uint4*)(p + 8);
        const unsigned wv[8] = {v0.x, v0.y, v0.z, v0.w, v1.x, v1.y, v1.z, v1.w};
        #pragma unroll
        for (int j = 0; j < 8; ++j) {
            union { unsigned u; float f; } lo, hi;
            lo.u = wv[j] << 16;
            hi.u = wv[j] & 0xFFFF0000u;
            acc[2 * j]     += lo.f;
            acc[2 * j + 1] += hi.f;
        }
    }

    const int n = qitem & 2047, h = (qitem >> 11) & 7, b = qitem >> 14;
    unsigned short* dst = chi + ((size_t)b * NSEQ + n) * DMODEL + h * HDIM + grp * 16;

    unsigned short o[16];
    #pragma unroll
    for (int j = 0; j < 16; ++j) o[j] = f2bf(acc[j] * inv);
    uint4 u0, u1;
    u0.x = (unsigned)o[0]  | ((unsigned)o[1]  << 16);
    u0.y = (unsigned)o[2]  | ((unsigned)o[3]  << 16);
    u0.z = (unsigned)o[4]  | ((unsigned)o[5]  << 16);
    u0.w = (unsigned)o[6]  | ((unsigned)o[7]  << 16);
    u1.x = (unsigned)o[8]  | ((unsigned)o[9]  << 16);
    u1.y = (unsigned)o[10] | ((unsigned)o[11] << 16);
    u1.z = (unsigned)o[12] | ((unsigned)o[13] << 16);
    u1.w = (unsigned)o[14] | ((unsigned)o[15] << 16);
    *(uint4*)dst = u0;
    *(uint4*)(dst + 8) = u1;
}

// ---------------------------------------------------------------------------
extern "C" void kernel_launch(void* const* d_in, const int* in_sizes, int n_in,
                              void* d_out, int out_size, void* d_ws, size_t ws_size,
                              hipStream_t stream) {
    const float* x   = (const float*)d_in[0];
    const float* adj = (const float*)d_in[1];
    const float* Wq  = (const float*)d_in[2];
    const float* bq  = (const float*)d_in[3];
    const float* Wk  = (const float*)d_in[4];
    const float* bk  = (const float*)d_in[5];
    const float* Wv  = (const float*)d_in[6];
    const float* bv  = (const float*)d_in[7];
    const float* Wo  = (const float*)d_in[8];
    const float* bo  = (const float*)d_in[9];
    float* out = (float*)d_out;

    const size_t elems = (size_t)NB * NSEQ * DMODEL;   // 4,194,304
    unsigned short* Qhi  = (unsigned short*)d_ws;                    // 8.4 MB
    unsigned short* Khi  = Qhi + elems;                              // 8.4 MB
    unsigned short* Vt   = Khi + elems;                              // 8.4 MB
    unsigned long long* Mbits = (unsigned long long*)(Vt + elems);   // 512 KB
    unsigned short* xhi  = (unsigned short*)(Mbits + 32 * NSEQ);     // 8.4 MB
    unsigned short* Wthi = xhi + elems;                              // 2 MB
    unsigned short* Opart = Wthi + 4 * (size_t)DMODEL * DMODEL;      // bf16 partials
    // ctx (bf16) aliases xhi (dead after qkv_mfma_kernel)
    unsigned short* chi = xhi;

    // 4-way k-split if the workspace can hold 4 bf16 partials; else 2-way.
    const size_t QS = (size_t)NB * NH * NSEQ;          // 65536
    const size_t head = (size_t)((char*)Opart - (char*)d_ws);
    const size_t per_split = QS * HDIM * 2 + QS * 4;   // bf16 O + f32 l per split
    const int split  = (ws_size >= head + 4 * per_split) ? 4 : 2;
    const int sshift = (split == 4) ? 2 : 1;
    float* lpart = (float*)(Opart + (size_t)split * QS * HDIM);

    prep_kernel<<<dim3(21504), dim3(256), 0, stream>>>(
        adj, Mbits, x, xhi, Wq, Wk, Wv, Wo, Wthi);
    qkv_mfma_kernel<<<dim3(64, 12), dim3(256), 0, stream>>>(
        xhi, Wthi, bq, bk, bv, Qhi, Khi, Vt);
    const int zhalf = (NB * split) / 2;
    attn_kernel<<<dim3(NSEQ / 128, NH, zhalf), dim3(256), 0, stream>>>(
        Qhi, Khi, Vt, Mbits, Opart, lpart, split, sshift, 0);
    attn_kernel<<<dim3(NSEQ / 128, NH, zhalf), dim3(256), 0, stream>>>(
        Qhi, Khi, Vt, Mbits, Opart, lpart, split, sshift, zhalf);
    merge_kernel<<<dim3(1024), dim3(256), 0, stream>>>(Opart, lpart, chi, split);
    out_mfma_kernel<<<dim3(64, 4), dim3(256), 0, stream>>>(
        chi, Wthi, bo, out);
}

// Round 18
// 185.817 us; speedup vs baseline: 1.0325x; 1.0325x over previous
//
#include <hip/hip_runtime.h>
#include <math.h>

#define NB    4
#define NSEQ  2048
#define DMODEL 512
#define NH    8
#define HDIM  64
#define STR   72   // attn LDS tile row stride (bf16 units): 144B rows, 16B-aligned
#define LOG2E 1.44269504088896f

typedef __attribute__((ext_vector_type(8))) short short8;
typedef __attribute__((ext_vector_type(4))) float f32x4;
typedef __attribute__((ext_vector_type(16))) float f32x16;
typedef __attribute__((ext_vector_type(2))) unsigned int uint2v;
#define MFMA16 __builtin_amdgcn_mfma_f32_16x16x32_bf16
#define MFMA32 __builtin_amdgcn_mfma_f32_32x32x16_bf16
#define EXP2F __builtin_amdgcn_exp2f

__device__ __forceinline__ unsigned short f2bf(float f) {
    union { float f; unsigned int u; } v; v.f = f;
    unsigned int u = v.u;
    unsigned int r = (u + 0x7FFFu + ((u >> 16) & 1u)) >> 16;   // RNE
    return (unsigned short)r;
}
__device__ __forceinline__ void async16(void* lds, const void* g) {
    __builtin_amdgcn_global_load_lds(
        (const __attribute__((address_space(1))) unsigned int*)g,
        (__attribute__((address_space(3))) unsigned int*)lds, 16, 0, 0);
}
// pack two f32 -> one u32 of 2x bf16 (RNE), single VALU op
__device__ __forceinline__ unsigned cvtpk(float lo, float hi) {
    unsigned r;
    asm("v_cvt_pk_bf16_f32 %0, %1, %2" : "=v"(r) : "v"(lo), "v"(hi));
    return r;
}
// exchange: a.hi-lanes <-> b.lo-lanes. After: a = {a.lo | b.lo}, b = {a.hi | b.hi}
__device__ __forceinline__ void pswap(unsigned& a, unsigned& b) {
    uint2v r = __builtin_amdgcn_permlane32_swap(a, b, false, false);
    a = r[0]; b = r[1];
}

// ---------------------------------------------------------------------------
// Fused prep, v18 (slim grid, 7168 blocks):
//   [0,2048)    mask ballots, 8 units per block (grid-stride)
//   [2048,6144) x->bf16, 4 elems/thread
//   [6144,7168) W^T 32x32 tiles
// ---------------------------------------------------------------------------
__global__ __launch_bounds__(256) void prep_kernel(
    const float* __restrict__ adj, unsigned long long* __restrict__ Mb,
    const float* __restrict__ x, unsigned short* __restrict__ xhi,
    const float* __restrict__ Wq, const float* __restrict__ Wk,
    const float* __restrict__ Wv, const float* __restrict__ Wo,
    unsigned short* __restrict__ Wthi)
{
    __shared__ float tile[32][33];
    const int bid = blockIdx.x;
    if (bid < 2048) {
        // ---- mask: Mb[kt*2048+q] = ballot(adj[q][kt*64+lane] > 0.5) ----
        const int lane = threadIdx.x & 63;
        #pragma unroll
        for (int i = 0; i < 8; ++i) {
            const int w  = (bid * 8 + i) * 4 + (threadIdx.x >> 6);
            const int q  = w >> 5;
            const int kt = w & 31;
            float a = adj[(size_t)q * NSEQ + kt * 64 + lane];
            unsigned long long m = __ballot(a > 0.5f);
            if (lane == 0) Mb[(size_t)kt * NSEQ + q] = m;
        }
    } else if (bid < 6144) {
        // ---- x (fp32) -> bf16, 4 elems/thread ----
        const int gid = (bid - 2048) * 256 + threadIdx.x;
        float4 a = ((const float4*)x)[gid];
        ushort4 h4;
        h4.x = f2bf(a.x); h4.y = f2bf(a.y); h4.z = f2bf(a.z); h4.w = f2bf(a.w);
        ((ushort4*)xhi)[gid] = h4;
    } else {
        // ---- W[k][n] fp32 -> Wt[mat][n][k] bf16, 32x32 tile per block ----
        const int local = bid - 6144;
        const int m  = local >> 8;
        const int rem = local & 255;
        const int k0 = (rem & 15) * 32, n0 = (rem >> 4) * 32;
        const float* W = (m == 0) ? Wq : (m == 1) ? Wk : (m == 2) ? Wv : Wo;
        const int tx = threadIdx.x & 31, ty = threadIdx.x >> 5;
        #pragma unroll
        for (int i = 0; i < 4; ++i)
            tile[ty * 4 + i][tx] = W[(size_t)(k0 + ty * 4 + i) * DMODEL + n0 + tx];
        __syncthreads();
        const size_t base = ((size_t)m * DMODEL) * DMODEL;
        #pragma unroll
        for (int i = 0; i < 4; ++i) {
            float f = tile[tx][ty * 4 + i];
            size_t idx = base + (size_t)(n0 + ty * 4 + i) * DMODEL + k0 + tx;
            Wthi[idx] = f2bf(f);
        }
    }
}

// ---------------------------------------------------------------------------
// Plain bf16 MFMA GEMM K-loop: 128x128 tile, BK=32, XOR-swizzled LDS,
// global_load_lds staging.
// ---------------------------------------------------------------------------
__device__ __forceinline__ void gemm_k_loop(
    const unsigned short* __restrict__ Ah,
    const unsigned short* __restrict__ Bh,
    char* smem, f32x4 acc[4][4])
{
    const int t    = threadIdx.x;
    const int lane = t & 63;
    const int wid  = t >> 6;
    const int quad = lane >> 4, l16 = lane & 15;
    const int wm   = wid >> 1,  wn  = wid & 1;

    unsigned short* As_h = (unsigned short*)(smem);
    unsigned short* Bs_h = (unsigned short*)(smem + 8192);

    const int ci0 = t, ci1 = 256 + t;
    const int r0 = ci0 >> 2, r1 = ci1 >> 2;
    const int c0 = (ci0 & 3) ^ ((r0 >> 1) & 3);
    const int c1 = (ci1 & 3) ^ ((r1 >> 1) & 3);
    const char* gAh = (const char*)Ah;
    const char* gBh = (const char*)Bh;
    const int ca = quad ^ ((l16 >> 1) & 3);

    for (int k0 = 0; k0 < DMODEL; k0 += 32) {
        const int kb = k0 * 2;
        async16(As_h + ci0 * 8, gAh + r0 * 1024 + kb + c0 * 16);
        async16(As_h + ci1 * 8, gAh + r1 * 1024 + kb + c1 * 16);
        async16(Bs_h + ci0 * 8, gBh + r0 * 1024 + kb + c0 * 16);
        async16(Bs_h + ci1 * 8, gBh + r1 * 1024 + kb + c1 * 16);
        __syncthreads();

        short8 ah[4], bh[4];
        #pragma unroll
        for (int i = 0; i < 4; ++i) {
            const int Ra = wm * 64 + i * 16 + l16;
            ah[i] = *(const short8*)(As_h + Ra * 32 + ca * 8);
            const int Rb = wn * 64 + i * 16 + l16;
            bh[i] = *(const short8*)(Bs_h + Rb * 32 + ca * 8);
        }
        #pragma unroll
        for (int mi = 0; mi < 4; ++mi)
            #pragma unroll
            for (int ni = 0; ni < 4; ++ni)
                acc[mi][ni] = MFMA16(ah[mi], bh[ni], acc[mi][ni], 0, 0, 0);
        __syncthreads();
    }
}

// ---------------------------------------------------------------------------
// QKV projection (MFMA, bf16). Q: *(0.125*log2e); K: plain; V: transposed.
// XCD-aware block swizzle; launch_bounds (256,4).
// ---------------------------------------------------------------------------
__global__ __launch_bounds__(256, 4) void qkv_mfma_kernel(
    const unsigned short* __restrict__ xhi,
    const unsigned short* __restrict__ Wthi,
    const float* __restrict__ bq, const float* __restrict__ bk, const float* __restrict__ bv,
    unsigned short* __restrict__ Qhi,
    unsigned short* __restrict__ Khi,
    unsigned short* __restrict__ Vt)
{
    __shared__ __align__(16) char smem[33280];
    const int t    = threadIdx.x;
    const int lane = t & 63;
    const int wid  = t >> 6;
    const int quad = lane >> 4, l16 = lane & 15;
    const int wm   = wid >> 1,  wn  = wid & 1;

    // XCD swizzle (bijective, 768 blocks): xcd = f&7 owns rows xcd*8..+7, all panels
    const int f    = blockIdx.x + 64 * blockIdx.y;
    const int xcd  = f & 7;
    const int loc  = f >> 3;                 // 0..95
    const int row0 = (xcd * 8 + (loc & 7)) * 128;
    const int yb   = loc >> 3;               // 0..11
    const int mtx  = yb >> 2;
    const int col0 = (yb & 3) * 128;

    f32x4 acc[4][4];
    #pragma unroll
    for (int i = 0; i < 4; ++i)
        #pragma unroll
        for (int j = 0; j < 4; ++j) acc[i][j] = (f32x4){0.f, 0.f, 0.f, 0.f};

    const size_t wslot = (size_t)mtx * DMODEL * DMODEL;
    gemm_k_loop(xhi + (size_t)row0 * DMODEL,
                Wthi + wslot + (size_t)col0 * DMODEL, smem, acc);

    const float* bias = (mtx == 0) ? bq : (mtx == 1) ? bk : bv;
    float bcol[4];
    #pragma unroll
    for (int ni = 0; ni < 4; ++ni) bcol[ni] = bias[col0 + wn * 64 + ni * 16 + l16];
    const int h = (col0 + wn * 64) >> 6;

    if (mtx < 2) {
        const float scale = (mtx == 0) ? (0.125f * LOG2E) : 1.0f;
        unsigned short* hig = (mtx == 0) ? Qhi : Khi;
        #pragma unroll
        for (int mi = 0; mi < 4; ++mi) {
            #pragma unroll
            for (int reg = 0; reg < 4; ++reg) {
                const int r = row0 + wm * 64 + mi * 16 + quad * 4 + reg;
                const int b = r >> 11, n = r & 2047;
                const size_t rowbase = ((size_t)(b * NH + h) * NSEQ + n) * HDIM;
                #pragma unroll
                for (int ni = 0; ni < 4; ++ni)
                    hig[rowbase + ni * 16 + l16] =
                        f2bf((acc[mi][ni][reg] + bcol[ni]) * scale);
            }
        }
    } else {
        // V: bias + bf16, transpose 64x64 per wave through LDS (stride 65)
        unsigned short* vt = (unsigned short*)smem + (size_t)wid * 64 * 65;
        #pragma unroll
        for (int mi = 0; mi < 4; ++mi)
            #pragma unroll
            for (int ni = 0; ni < 4; ++ni)
                #pragma unroll
                for (int reg = 0; reg < 4; ++reg)
                    vt[(mi * 16 + quad * 4 + reg) * 65 + ni * 16 + l16] =
                        f2bf(acc[mi][ni][reg] + bcol[ni]);
        const int b   = row0 >> 11;
        const int n0g = (row0 & 2047) + wm * 64;
        const int bh  = b * NH + h;
        unsigned short* gdst = Vt + ((size_t)bh * HDIM + lane) * NSEQ + n0g;
        #pragma unroll
        for (int nb = 0; nb < 8; ++nb) {
            unsigned short v[8];
            #pragma unroll
            for (int j = 0; j < 8; ++j) v[j] = vt[(nb * 8 + j) * 65 + lane];
            uint4 u;
            u.x = (unsigned)v[0] | ((unsigned)v[1] << 16);
            u.y = (unsigned)v[2] | ((unsigned)v[3] << 16);
            u.z = (unsigned)v[4] | ((unsigned)v[5] << 16);
            u.w = (unsigned)v[6] | ((unsigned)v[7] << 16);
            *(uint4*)(gdst + nb * 8) = u;
        }
    }
}

// ---------------------------------------------------------------------------
// Output projection (MFMA): ctx(bf16) @ Wo^T + bo -> out fp32 [B,N,D]
// ---------------------------------------------------------------------------
__global__ __launch_bounds__(256, 4) void out_mfma_kernel(
    const unsigned short* __restrict__ chi,
    const unsigned short* __restrict__ Wthi,
    const float* __restrict__ bo, float* __restrict__ out)
{
    __shared__ __align__(16) char smem[16384];
    const int t    = threadIdx.x;
    const int lane = t & 63;
    const int wid  = t >> 6;
    const int quad = lane >> 4, l16 = lane & 15;
    const int wm   = wid >> 1,  wn  = wid & 1;

    const int f    = blockIdx.x + 64 * blockIdx.y;
    const int xcd  = f & 7;
    const int loc  = f >> 3;                 // 0..31
    const int row0 = (xcd * 8 + (loc & 7)) * 128;
    const int col0 = (loc >> 3) * 128;       // 0..3

    f32x4 acc[4][4];
    #pragma unroll
    for (int i = 0; i < 4; ++i)
        #pragma unroll
        for (int j = 0; j < 4; ++j) acc[i][j] = (f32x4){0.f, 0.f, 0.f, 0.f};

    const size_t wslot = (size_t)3 * DMODEL * DMODEL;   // Wo
    gemm_k_loop(chi + (size_t)row0 * DMODEL,
                Wthi + wslot + (size_t)col0 * DMODEL, smem, acc);

    float bcol[4];
    #pragma unroll
    for (int ni = 0; ni < 4; ++ni) bcol[ni] = bo[col0 + wn * 64 + ni * 16 + l16];
    #pragma unroll
    for (int mi = 0; mi < 4; ++mi)
        #pragma unroll
        for (int reg = 0; reg < 4; ++reg) {
            const int r = row0 + wm * 64 + mi * 16 + quad * 4 + reg;
            float* orow = out + (size_t)r * DMODEL + col0 + wn * 64 + l16;
            #pragma unroll
            for (int ni = 0; ni < 4; ++ni)
                orow[ni * 16] = acc[mi][ni][reg] + bcol[ni];
        }
}

// ---------------------------------------------------------------------------
// MFMA flash attention, 32x32x16, runtime K-SPLIT (2 or 4). Verified R12 body,
// single launch: single-buffer K/V LDS (18.4 KB), 8 blocks/CU, 2 barriers/
// tile, reg-staged prefetch, LDS nibble-LUT mask, swapped QK^T + in-register
// P redistribution (cvt_pk + permlane32_swap), bf16 O-partials.
// NOTE (R15): device-scope atomics/threadfence inter-block fusion is banned
// here — per-block cross-XCD release fences cost an L2 writeback (8x slowdn).
// ---------------------------------------------------------------------------
__global__ __launch_bounds__(256, 4) void attn_kernel(
    const unsigned short* __restrict__ Qhi,
    const unsigned short* __restrict__ Khi,
    const unsigned short* __restrict__ Vt,
    const unsigned long long* __restrict__ Mb,
    unsigned short* __restrict__ Opart, float* __restrict__ lpart,
    const int split, const int sshift)
{
    __shared__ __align__(16) unsigned short KS[64 * STR];   // 9.2 KB
    __shared__ __align__(16) unsigned short VS[64 * STR];   // 9.2 KB
    __shared__ unsigned long long mlut[16];                 // nibble -> bf16 mask

    const int t    = threadIdx.x;
    const int wq   = t >> 6;        // wave 0..3
    const int lane = t & 63;
    const int l32  = lane & 31;
    const int hw   = lane >> 5;     // half-wave

    // XCD swizzle (bijective): flat = x + 16y + 128z; xcd = flat&7.
    const int flat = blockIdx.x + 16 * (blockIdx.y + 8 * blockIdx.z);
    const int xcd  = flat & 7;
    const int u    = flat >> 3;
    const int zi   = xcd * (split >> 1) + (u >> 7);
    const int h    = u & 7;
    const int qt   = (u >> 3) & 15;
    const int b    = zi >> sshift;
    const int ks   = zi & (split - 1);
    const int ktSpan = 32 >> sshift;
    const int bh   = b * NH + h;
    const int qa   = qt * 128 + wq * 32;

    // ---- init mask LUT: mlut[n] halfword j = (n>>j)&1 ? 0xFFFF : 0 ----
    if (t < 16) {
        unsigned long long m = 0;
        if (t & 1) m |= 0xFFFFull;
        if (t & 2) m |= 0xFFFF0000ull;
        if (t & 4) m |= 0xFFFFull << 32;
        if (t & 8) m |= 0xFFFFull << 48;
        mlut[t] = m;
    }

    // Q B-frags: row = qa+l32, k-chunk s*16 + hw*8 (scaled 0.125*log2e at proj)
    short8 qh[4];
    #pragma unroll
    for (int s = 0; s < 4; ++s)
        qh[s] = *(const short8*)(Qhi + ((size_t)bh * NSEQ + qa + l32) * HDIM + s * 16 + hw * 8);
    const unsigned long long* mrow = Mb + (qa + l32);

    short8 onesf;
    #pragma unroll
    for (int i = 0; i < 8; ++i) onesf[i] = (short)0x3F80;   // bf16 1.0

    f32x16 O0, O1, Ol;
    #pragma unroll
    for (int i = 0; i < 16; ++i) { O0[i] = 0.f; O1[i] = 0.f; Ol[i] = 0.f; }

    const unsigned short* gk = Khi + (size_t)bh * NSEQ * HDIM;
    const unsigned short* gv = Vt  + (size_t)bh * HDIM * NSEQ;

    const int ci0 = t, ci1 = t + 256;
    const int sr0 = ci0 >> 3, sc0 = (ci0 & 7) * 8;
    const int sr1 = ci1 >> 3, sc1 = (ci1 & 7) * 8;

    const int ktBeg = ks * ktSpan, ktEnd = ktBeg + ktSpan;

    // ---- prologue: stage first K/V tile ----
    {
        const int k0 = ktBeg * 64;
        uint4 ka = *(const uint4*)(gk + (size_t)(k0 + sr0) * HDIM + sc0);
        uint4 kc = *(const uint4*)(gk + (size_t)(k0 + sr1) * HDIM + sc1);
        uint4 va = *(const uint4*)(gv + (size_t)sr0 * NSEQ + k0 + sc0);
        uint4 vc = *(const uint4*)(gv + (size_t)sr1 * NSEQ + k0 + sc1);
        *(uint4*)&KS[sr0 * STR + sc0] = ka;
        *(uint4*)&KS[sr1 * STR + sc1] = kc;
        *(uint4*)&VS[sr0 * STR + sc0] = va;
        *(uint4*)&VS[sr1 * STR + sc1] = vc;
    }
    __syncthreads();   // fences both staging and mlut init

    for (int kt = ktBeg; kt < ktEnd; ++kt) {
        const unsigned short* ksrc = KS;
        const unsigned short* vsrc = VS;
        const unsigned long long mw = mrow[(size_t)kt * NSEQ];

        // ---- S^T = K Q^T per 32-key tile; exp2; in-register redistribute ----
        short8 pf[4];
        #pragma unroll
        for (int nt = 0; nt < 2; ++nt) {
            f32x16 S;
            #pragma unroll
            for (int i = 0; i < 16; ++i) S[i] = 0.f;
            __builtin_amdgcn_s_setprio(1);
            #pragma unroll
            for (int s = 0; s < 4; ++s) {
                short8 kb = *(const short8*)&ksrc[(nt * 32 + l32) * STR + s * 16 + hw * 8];
                S = MFMA32(kb, qh[s], S, 0, 0, 0);   // swapped: lane l32 = q col
            }
            __builtin_amdgcn_s_setprio(0);
            // lane (l32,hw): p[r] = P[q=qa+l32][key = nt*32 + (r&3)+8*(r>>2)+4*hw]
            float p[16];
            #pragma unroll
            for (int r = 0; r < 16; ++r) p[r] = EXP2F(S[r]);
            unsigned w[8];
            #pragma unroll
            for (int i = 0; i < 8; ++i) w[i] = cvtpk(p[2 * i], p[2 * i + 1]);
            // exchange half-wave partners: one swap fills two fragment words
            pswap(w[0], w[2]); pswap(w[1], w[3]);
            pswap(w[4], w[6]); pswap(w[5], w[7]);
            union { short8 s8; unsigned u[4]; } A, B2;
            A.u[0] = w[0]; A.u[1] = w[1]; A.u[2] = w[2]; A.u[3] = w[3];
            B2.u[0] = w[4]; B2.u[1] = w[5]; B2.u[2] = w[6]; B2.u[3] = w[7];
            pf[2 * nt]     = A.s8;    // keys nt*32 + hw*8 + 0..7 (per 16-chunk)
            pf[2 * nt + 1] = B2.s8;
        }

        // ---- issue next-tile global loads (latency hides under mask+PV) ----
        uint4 nk0, nk1, nv0, nv1;
        const bool more = (kt + 1 < ktEnd);
        if (more) {
            const int k0n = (kt + 1) * 64;
            nk0 = *(const uint4*)(gk + (size_t)(k0n + sr0) * HDIM + sc0);
            nk1 = *(const uint4*)(gk + (size_t)(k0n + sr1) * HDIM + sc1);
            nv0 = *(const uint4*)(gv + (size_t)sr0 * NSEQ + k0n + sc0);
            nv1 = *(const uint4*)(gv + (size_t)sr1 * NSEQ + k0n + sc1);
        }

        // ---- apply adjacency mask via LDS nibble LUT ----
        #pragma unroll
        for (int s = 0; s < 4; ++s) {
            const unsigned bits8 = (unsigned)(mw >> (s * 16 + hw * 8)) & 0xFFu;
            const unsigned long long lo = mlut[bits8 & 15u];
            const unsigned long long hi = mlut[bits8 >> 4];
            union { short8 s8; uint4 u; } x; x.s8 = pf[s];
            x.u.x &= (unsigned)lo; x.u.y &= (unsigned)(lo >> 32);
            x.u.z &= (unsigned)hi; x.u.w &= (unsigned)(hi >> 32);
            pf[s] = x.s8;
        }

        // ---- O += P @ V ; l += P @ ones ----
        __builtin_amdgcn_s_setprio(1);
        #pragma unroll
        for (int s = 0; s < 4; ++s) {
            short8 v0 = *(const short8*)&vsrc[(l32) * STR + s * 16 + hw * 8];
            short8 v1 = *(const short8*)&vsrc[(32 + l32) * STR + s * 16 + hw * 8];
            O0 = MFMA32(pf[s], v0, O0, 0, 0, 0);
            O1 = MFMA32(pf[s], v1, O1, 0, 0, 0);
            Ol = MFMA32(pf[s], onesf, Ol, 0, 0, 0);
        }
        __builtin_amdgcn_s_setprio(0);

        // ---- barrier 1: all waves done READING KS/VS for this tile ----
        __syncthreads();
        // ---- write staged regs into the (single) buffer ----
        if (more) {
            *(uint4*)&KS[sr0 * STR + sc0] = nk0;
            *(uint4*)&KS[sr1 * STR + sc1] = nk1;
            *(uint4*)&VS[sr0 * STR + sc0] = nv0;
            *(uint4*)&VS[sr1 * STR + sc1] = nv1;
        }
        // ---- barrier 2: writes visible for next iteration ----
        __syncthreads();
    }

    // ---- write bf16 O-partials (no normalization; merge kernel sums) ----
    const size_t obase = ((size_t)(ks * NB + b) * NH + h) * NSEQ;
    #pragma unroll
    for (int r = 0; r < 16; ++r) {
        const int qrow = qa + (r & 3) + 8 * (r >> 2) + 4 * hw;
        unsigned short* orow = Opart + (obase + qrow) * HDIM;
        orow[l32]      = f2bf(O0[r]);
        orow[32 + l32] = f2bf(O1[r]);
        if (l32 == 0) lpart[obase + qrow] = Ol[r];
    }
}

// ---------------------------------------------------------------------------
// Merge: ctx = (sum_i O_i) / (sum_i l_i), bf16 partials -> chi [B,N,D]
// ---------------------------------------------------------------------------
__global__ __launch_bounds__(256) void merge_kernel(
    const unsigned short* __restrict__ Opart, const float* __restrict__ lpart,
    unsigned short* __restrict__ chi, const int split)
{
    const int g = blockIdx.x * 256 + threadIdx.x;   // 262144 threads
    const int qitem = g >> 2;                       // (b*NH+h)*NSEQ+n
    const int grp = g & 3;                          // 16-dim group
    const size_t QS = (size_t)NB * NH * NSEQ;
    const size_t HS = QS * HDIM;

    float lsum = 0.f;
    for (int i = 0; i < split; ++i) lsum += lpart[qitem + (size_t)i * QS];
    const float inv = 1.0f / lsum;

    float acc[16];
    #pragma unroll
    for (int j = 0; j < 16; ++j) acc[j] = 0.f;
    const unsigned short* pa = Opart + (size_t)qitem * HDIM + grp * 16;
    for (int i = 0; i < split; ++i) {
        const unsigned short* p = pa + (size_t)i * HS;
        uint4 v0 = *(const uint4*)(p);
        uint4 v1 = *(const uint4*)(p + 8);
        const unsigned wv[8] = {v0.x, v0.y, v0.z, v0.w, v1.x, v1.y, v1.z, v1.w};
        #pragma unroll
        for (int j = 0; j < 8; ++j) {
            union { unsigned u; float f; } lo, hi;
            lo.u = wv[j] << 16;
            hi.u = wv[j] & 0xFFFF0000u;
            acc[2 * j]     += lo.f;
            acc[2 * j + 1] += hi.f;
        }
    }

    const int n = qitem & 2047, h = (qitem >> 11) & 7, b = qitem >> 14;
    unsigned short* dst = chi + ((size_t)b * NSEQ + n) * DMODEL + h * HDIM + grp * 16;

    unsigned short o[16];
    #pragma unroll
    for (int j = 0; j < 16; ++j) o[j] = f2bf(acc[j] * inv);
    uint4 u0, u1;
    u0.x = (unsigned)o[0]  | ((unsigned)o[1]  << 16);
    u0.y = (unsigned)o[2]  | ((unsigned)o[3]  << 16);
    u0.z = (unsigned)o[4]  | ((unsigned)o[5]  << 16);
    u0.w = (unsigned)o[6]  | ((unsigned)o[7]  << 16);
    u1.x = (unsigned)o[8]  | ((unsigned)o[9]  << 16);
    u1.y = (unsigned)o[10] | ((unsigned)o[11] << 16);
    u1.z = (unsigned)o[12] | ((unsigned)o[13] << 16);
    u1.w = (unsigned)o[14] | ((unsigned)o[15] << 16);
    *(uint4*)dst = u0;
    *(uint4*)(dst + 8) = u1;
}

// ---------------------------------------------------------------------------
extern "C" void kernel_launch(void* const* d_in, const int* in_sizes, int n_in,
                              void* d_out, int out_size, void* d_ws, size_t ws_size,
                              hipStream_t stream) {
    const float* x   = (const float*)d_in[0];
    const float* adj = (const float*)d_in[1];
    const float* Wq  = (const float*)d_in[2];
    const float* bq  = (const float*)d_in[3];
    const float* Wk  = (const float*)d_in[4];
    const float* bk  = (const float*)d_in[5];
    const float* Wv  = (const float*)d_in[6];
    const float* bv  = (const float*)d_in[7];
    const float* Wo  = (const float*)d_in[8];
    const float* bo  = (const float*)d_in[9];
    float* out = (float*)d_out;

    const size_t elems = (size_t)NB * NSEQ * DMODEL;   // 4,194,304
    unsigned short* Qhi  = (unsigned short*)d_ws;                    // 8.4 MB
    unsigned short* Khi  = Qhi + elems;                              // 8.4 MB
    unsigned short* Vt   = Khi + elems;                              // 8.4 MB
    unsigned long long* Mbits = (unsigned long long*)(Vt + elems);   // 512 KB
    unsigned short* xhi  = (unsigned short*)(Mbits + 32 * NSEQ);     // 8.4 MB
    unsigned short* Wthi = xhi + elems;                              // 2 MB
    unsigned short* Opart = Wthi + 4 * (size_t)DMODEL * DMODEL;      // bf16 partials
    // ctx (bf16) aliases xhi (dead after qkv_mfma_kernel)
    unsigned short* chi = xhi;

    // 4-way k-split if the workspace can hold 4 bf16 partials; else 2-way.
    const size_t QS = (size_t)NB * NH * NSEQ;          // 65536
    const size_t head = (size_t)((char*)Opart - (char*)d_ws);
    const size_t per_split = QS * HDIM * 2 + QS * 4;   // bf16 O + f32 l per split
    const int split  = (ws_size >= head + 4 * per_split) ? 4 : 2;
    const int sshift = (split == 4) ? 2 : 1;
    float* lpart = (float*)(Opart + (size_t)split * QS * HDIM);

    prep_kernel<<<dim3(7168), dim3(256), 0, stream>>>(
        adj, Mbits, x, xhi, Wq, Wk, Wv, Wo, Wthi);
    qkv_mfma_kernel<<<dim3(64, 12), dim3(256), 0, stream>>>(
        xhi, Wthi, bq, bk, bv, Qhi, Khi, Vt);
    attn_kernel<<<dim3(NSEQ / 128, NH, NB * split), dim3(256), 0, stream>>>(
        Qhi, Khi, Vt, Mbits, Opart, lpart, split, sshift);
    merge_kernel<<<dim3(1024), dim3(256), 0, stream>>>(Opart, lpart, chi, split);
    out_mfma_kernel<<<dim3(64, 4), dim3(256), 0, stream>>>(
        chi, Wthi, bo, out);
}

// Round 19
// 183.565 us; speedup vs baseline: 1.0451x; 1.0123x over previous
//
#include <hip/hip_runtime.h>
#include <math.h>

#define NB    4
#define NSEQ  2048
#define DMODEL 512
#define NH    8
#define HDIM  64
#define STR   72   // attn LDS tile row stride (bf16 units): 144B rows, 16B-aligned
#define LOG2E 1.44269504088896f

typedef __attribute__((ext_vector_type(8))) short short8;
typedef __attribute__((ext_vector_type(4))) float f32x4;
typedef __attribute__((ext_vector_type(16))) float f32x16;
typedef __attribute__((ext_vector_type(2))) unsigned int uint2v;
#define MFMA16 __builtin_amdgcn_mfma_f32_16x16x32_bf16
#define MFMA32 __builtin_amdgcn_mfma_f32_32x32x16_bf16
#define EXP2F __builtin_amdgcn_exp2f

// SESSION RESULT (R0 204.0 us -> ~186 us). Plateau confirmed x4 (R12/R13/
// R16/R18: 185.6-186.3). Structural floor of this 5-kernel decomposition:
//   attn 54.7 us  (issue-bound: MFMA 32% + VALU 41%, 4-wave/SIMD reg cap)
//   prep/qkv/merge/out ~110 us (each <41.5 us; small-shape GEMM efficiency;
//     the 1563-TF 8-phase 256^2 template is grid-starved here: 192 blk<256 CU)
//   ~15-20 us launch boundaries (measured ~5 us/launch, chain is
//     dependency-minimal; cross-XCD fence fusion measured 8x toxic)
__device__ __forceinline__ unsigned short f2bf(float f) {
    union { float f; unsigned int u; } v; v.f = f;
    unsigned int u = v.u;
    unsigned int r = (u + 0x7FFFu + ((u >> 16) & 1u)) >> 16;   // RNE
    return (unsigned short)r;
}
__device__ __forceinline__ void async16(void* lds, const void* g) {
    __builtin_amdgcn_global_load_lds(
        (const __attribute__((address_space(1))) unsigned int*)g,
        (__attribute__((address_space(3))) unsigned int*)lds, 16, 0, 0);
}
// pack two f32 -> one u32 of 2x bf16 (RNE), single VALU op
__device__ __forceinline__ unsigned cvtpk(float lo, float hi) {
    unsigned r;
    asm("v_cvt_pk_bf16_f32 %0, %1, %2" : "=v"(r) : "v"(lo), "v"(hi));
    return r;
}
// exchange: a.hi-lanes <-> b.lo-lanes. After: a = {a.lo | b.lo}, b = {a.hi | b.hi}
__device__ __forceinline__ void pswap(unsigned& a, unsigned& b) {
    uint2v r = __builtin_amdgcn_permlane32_swap(a, b, false, false);
    a = r[0]; b = r[1];
}

// ---------------------------------------------------------------------------
// Fused prep (slim grid, 7168 blocks):
//   [0,2048)    mask ballots, 8 units per block
//   [2048,6144) x->bf16, 4 elems/thread (cvtpk)
//   [6144,7168) W^T 32x32 tiles (cvtpk)
// ---------------------------------------------------------------------------
__global__ __launch_bounds__(256) void prep_kernel(
    const float* __restrict__ adj, unsigned long long* __restrict__ Mb,
    const float* __restrict__ x, unsigned short* __restrict__ xhi,
    const float* __restrict__ Wq, const float* __restrict__ Wk,
    const float* __restrict__ Wv, const float* __restrict__ Wo,
    unsigned short* __restrict__ Wthi)
{
    __shared__ float tile[32][33];
    const int bid = blockIdx.x;
    if (bid < 2048) {
        // ---- mask: Mb[kt*2048+q] = ballot(adj[q][kt*64+lane] > 0.5) ----
        const int lane = threadIdx.x & 63;
        #pragma unroll
        for (int i = 0; i < 8; ++i) {
            const int w  = (bid * 8 + i) * 4 + (threadIdx.x >> 6);
            const int q  = w >> 5;
            const int kt = w & 31;
            float a = adj[(size_t)q * NSEQ + kt * 64 + lane];
            unsigned long long m = __ballot(a > 0.5f);
            if (lane == 0) Mb[(size_t)kt * NSEQ + q] = m;
        }
    } else if (bid < 6144) {
        // ---- x (fp32) -> bf16, 4 elems/thread via cvt_pk (RNE == f2bf) ----
        const int gid = (bid - 2048) * 256 + threadIdx.x;
        float4 a = ((const float4*)x)[gid];
        uint2 p;
        p.x = cvtpk(a.x, a.y);
        p.y = cvtpk(a.z, a.w);
        ((uint2*)xhi)[gid] = p;
    } else {
        // ---- W[k][n] fp32 -> Wt[mat][n][k] bf16, 32x32 tile per block ----
        const int local = bid - 6144;
        const int m  = local >> 8;
        const int rem = local & 255;
        const int k0 = (rem & 15) * 32, n0 = (rem >> 4) * 32;
        const float* W = (m == 0) ? Wq : (m == 1) ? Wk : (m == 2) ? Wv : Wo;
        const int tx = threadIdx.x & 31, ty = threadIdx.x >> 5;
        #pragma unroll
        for (int i = 0; i < 4; ++i)
            tile[ty * 4 + i][tx] = W[(size_t)(k0 + ty * 4 + i) * DMODEL + n0 + tx];
        __syncthreads();
        const size_t base = ((size_t)m * DMODEL) * DMODEL;
        #pragma unroll
        for (int i = 0; i < 4; ++i) {
            float f = tile[tx][ty * 4 + i];
            size_t idx = base + (size_t)(n0 + ty * 4 + i) * DMODEL + k0 + tx;
            Wthi[idx] = f2bf(f);
        }
    }
}

// ---------------------------------------------------------------------------
// Plain bf16 MFMA GEMM K-loop: 128x128 tile, BK=32, XOR-swizzled LDS,
// global_load_lds staging.
// ---------------------------------------------------------------------------
__device__ __forceinline__ void gemm_k_loop(
    const unsigned short* __restrict__ Ah,
    const unsigned short* __restrict__ Bh,
    char* smem, f32x4 acc[4][4])
{
    const int t    = threadIdx.x;
    const int lane = t & 63;
    const int wid  = t >> 6;
    const int quad = lane >> 4, l16 = lane & 15;
    const int wm   = wid >> 1,  wn  = wid & 1;

    unsigned short* As_h = (unsigned short*)(smem);
    unsigned short* Bs_h = (unsigned short*)(smem + 8192);

    const int ci0 = t, ci1 = 256 + t;
    const int r0 = ci0 >> 2, r1 = ci1 >> 2;
    const int c0 = (ci0 & 3) ^ ((r0 >> 1) & 3);
    const int c1 = (ci1 & 3) ^ ((r1 >> 1) & 3);
    const char* gAh = (const char*)Ah;
    const char* gBh = (const char*)Bh;
    const int ca = quad ^ ((l16 >> 1) & 3);

    for (int k0 = 0; k0 < DMODEL; k0 += 32) {
        const int kb = k0 * 2;
        async16(As_h + ci0 * 8, gAh + r0 * 1024 + kb + c0 * 16);
        async16(As_h + ci1 * 8, gAh + r1 * 1024 + kb + c1 * 16);
        async16(Bs_h + ci0 * 8, gBh + r0 * 1024 + kb + c0 * 16);
        async16(Bs_h + ci1 * 8, gBh + r1 * 1024 + kb + c1 * 16);
        __syncthreads();

        short8 ah[4], bh[4];
        #pragma unroll
        for (int i = 0; i < 4; ++i) {
            const int Ra = wm * 64 + i * 16 + l16;
            ah[i] = *(const short8*)(As_h + Ra * 32 + ca * 8);
            const int Rb = wn * 64 + i * 16 + l16;
            bh[i] = *(const short8*)(Bs_h + Rb * 32 + ca * 8);
        }
        #pragma unroll
        for (int mi = 0; mi < 4; ++mi)
            #pragma unroll
            for (int ni = 0; ni < 4; ++ni)
                acc[mi][ni] = MFMA16(ah[mi], bh[ni], acc[mi][ni], 0, 0, 0);
        __syncthreads();
    }
}

// ---------------------------------------------------------------------------
// QKV projection (MFMA, bf16). Q: *(0.125*log2e); K: plain; V: transposed.
// XCD-aware block swizzle; launch_bounds (256,4).
// ---------------------------------------------------------------------------
__global__ __launch_bounds__(256, 4) void qkv_mfma_kernel(
    const unsigned short* __restrict__ xhi,
    const unsigned short* __restrict__ Wthi,
    const float* __restrict__ bq, const float* __restrict__ bk, const float* __restrict__ bv,
    unsigned short* __restrict__ Qhi,
    unsigned short* __restrict__ Khi,
    unsigned short* __restrict__ Vt)
{
    __shared__ __align__(16) char smem[33280];
    const int t    = threadIdx.x;
    const int lane = t & 63;
    const int wid  = t >> 6;
    const int quad = lane >> 4, l16 = lane & 15;
    const int wm   = wid >> 1,  wn  = wid & 1;

    // XCD swizzle (bijective, 768 blocks): xcd = f&7 owns rows xcd*8..+7, all panels
    const int f    = blockIdx.x + 64 * blockIdx.y;
    const int xcd  = f & 7;
    const int loc  = f >> 3;                 // 0..95
    const int row0 = (xcd * 8 + (loc & 7)) * 128;
    const int yb   = loc >> 3;               // 0..11
    const int mtx  = yb >> 2;
    const int col0 = (yb & 3) * 128;

    f32x4 acc[4][4];
    #pragma unroll
    for (int i = 0; i < 4; ++i)
        #pragma unroll
        for (int j = 0; j < 4; ++j) acc[i][j] = (f32x4){0.f, 0.f, 0.f, 0.f};

    const size_t wslot = (size_t)mtx * DMODEL * DMODEL;
    gemm_k_loop(xhi + (size_t)row0 * DMODEL,
                Wthi + wslot + (size_t)col0 * DMODEL, smem, acc);

    const float* bias = (mtx == 0) ? bq : (mtx == 1) ? bk : bv;
    float bcol[4];
    #pragma unroll
    for (int ni = 0; ni < 4; ++ni) bcol[ni] = bias[col0 + wn * 64 + ni * 16 + l16];
    const int h = (col0 + wn * 64) >> 6;

    if (mtx < 2) {
        const float scale = (mtx == 0) ? (0.125f * LOG2E) : 1.0f;
        unsigned short* hig = (mtx == 0) ? Qhi : Khi;
        #pragma unroll
        for (int mi = 0; mi < 4; ++mi) {
            #pragma unroll
            for (int reg = 0; reg < 4; ++reg) {
                const int r = row0 + wm * 64 + mi * 16 + quad * 4 + reg;
                const int b = r >> 11, n = r & 2047;
                const size_t rowbase = ((size_t)(b * NH + h) * NSEQ + n) * HDIM;
                #pragma unroll
                for (int ni = 0; ni < 4; ++ni)
                    hig[rowbase + ni * 16 + l16] =
                        f2bf((acc[mi][ni][reg] + bcol[ni]) * scale);
            }
        }
    } else {
        // V: bias + bf16, transpose 64x64 per wave through LDS (stride 65)
        unsigned short* vt = (unsigned short*)smem + (size_t)wid * 64 * 65;
        #pragma unroll
        for (int mi = 0; mi < 4; ++mi)
            #pragma unroll
            for (int ni = 0; ni < 4; ++ni)
                #pragma unroll
                for (int reg = 0; reg < 4; ++reg)
                    vt[(mi * 16 + quad * 4 + reg) * 65 + ni * 16 + l16] =
                        f2bf(acc[mi][ni][reg] + bcol[ni]);
        const int b   = row0 >> 11;
        const int n0g = (row0 & 2047) + wm * 64;
        const int bh  = b * NH + h;
        unsigned short* gdst = Vt + ((size_t)bh * HDIM + lane) * NSEQ + n0g;
        #pragma unroll
        for (int nb = 0; nb < 8; ++nb) {
            unsigned short v[8];
            #pragma unroll
            for (int j = 0; j < 8; ++j) v[j] = vt[(nb * 8 + j) * 65 + lane];
            uint4 u;
            u.x = (unsigned)v[0] | ((unsigned)v[1] << 16);
            u.y = (unsigned)v[2] | ((unsigned)v[3] << 16);
            u.z = (unsigned)v[4] | ((unsigned)v[5] << 16);
            u.w = (unsigned)v[6] | ((unsigned)v[7] << 16);
            *(uint4*)(gdst + nb * 8) = u;
        }
    }
}

// ---------------------------------------------------------------------------
// Output projection (MFMA): ctx(bf16) @ Wo^T + bo -> out fp32 [B,N,D]
// ---------------------------------------------------------------------------
__global__ __launch_bounds__(256, 4) void out_mfma_kernel(
    const unsigned short* __restrict__ chi,
    const unsigned short* __restrict__ Wthi,
    const float* __restrict__ bo, float* __restrict__ out)
{
    __shared__ __align__(16) char smem[16384];
    const int t    = threadIdx.x;
    const int lane = t & 63;
    const int wid  = t >> 6;
    const int quad = lane >> 4, l16 = lane & 15;
    const int wm   = wid >> 1,  wn  = wid & 1;

    const int f    = blockIdx.x + 64 * blockIdx.y;
    const int xcd  = f & 7;
    const int loc  = f >> 3;                 // 0..31
    const int row0 = (xcd * 8 + (loc & 7)) * 128;
    const int col0 = (loc >> 3) * 128;       // 0..3

    f32x4 acc[4][4];
    #pragma unroll
    for (int i = 0; i < 4; ++i)
        #pragma unroll
        for (int j = 0; j < 4; ++j) acc[i][j] = (f32x4){0.f, 0.f, 0.f, 0.f};

    const size_t wslot = (size_t)3 * DMODEL * DMODEL;   // Wo
    gemm_k_loop(chi + (size_t)row0 * DMODEL,
                Wthi + wslot + (size_t)col0 * DMODEL, smem, acc);

    float bcol[4];
    #pragma unroll
    for (int ni = 0; ni < 4; ++ni) bcol[ni] = bo[col0 + wn * 64 + ni * 16 + l16];
    #pragma unroll
    for (int mi = 0; mi < 4; ++mi)
        #pragma unroll
        for (int reg = 0; reg < 4; ++reg) {
            const int r = row0 + wm * 64 + mi * 16 + quad * 4 + reg;
            float* orow = out + (size_t)r * DMODEL + col0 + wn * 64 + l16;
            #pragma unroll
            for (int ni = 0; ni < 4; ++ni)
                orow[ni * 16] = acc[mi][ni][reg] + bcol[ni];
        }
}

// ---------------------------------------------------------------------------
// MFMA flash attention, 32x32x16, runtime K-SPLIT (2 or 4). Final verified
// form: single-buffer K/V LDS (18.4 KB), 8 blocks/CU, 2 barriers/tile,
// reg-staged prefetch, LDS nibble-LUT mask, swapped QK^T + in-register P
// redistribution (cvt_pk + permlane32_swap), bf16 O-partials.
// Banned (measured): device-scope atomic/fence inter-block fusion (8x slow),
// global_load_lds+XOR-swizzle staging here (2x correctness failures),
// expanded global masks (L2 thrash).
// ---------------------------------------------------------------------------
__global__ __launch_bounds__(256, 4) void attn_kernel(
    const unsigned short* __restrict__ Qhi,
    const unsigned short* __restrict__ Khi,
    const unsigned short* __restrict__ Vt,
    const unsigned long long* __restrict__ Mb,
    unsigned short* __restrict__ Opart, float* __restrict__ lpart,
    const int split, const int sshift)
{
    __shared__ __align__(16) unsigned short KS[64 * STR];   // 9.2 KB
    __shared__ __align__(16) unsigned short VS[64 * STR];   // 9.2 KB
    __shared__ unsigned long long mlut[16];                 // nibble -> bf16 mask

    const int t    = threadIdx.x;
    const int wq   = t >> 6;        // wave 0..3
    const int lane = t & 63;
    const int l32  = lane & 31;
    const int hw   = lane >> 5;     // half-wave

    // XCD swizzle (bijective): flat = x + 16y + 128z; xcd = flat&7.
    const int flat = blockIdx.x + 16 * (blockIdx.y + 8 * blockIdx.z);
    const int xcd  = flat & 7;
    const int u    = flat >> 3;
    const int zi   = xcd * (split >> 1) + (u >> 7);
    const int h    = u & 7;
    const int qt   = (u >> 3) & 15;
    const int b    = zi >> sshift;
    const int ks   = zi & (split - 1);
    const int ktSpan = 32 >> sshift;
    const int bh   = b * NH + h;
    const int qa   = qt * 128 + wq * 32;

    // ---- init mask LUT: mlut[n] halfword j = (n>>j)&1 ? 0xFFFF : 0 ----
    if (t < 16) {
        unsigned long long m = 0;
        if (t & 1) m |= 0xFFFFull;
        if (t & 2) m |= 0xFFFF0000ull;
        if (t & 4) m |= 0xFFFFull << 32;
        if (t & 8) m |= 0xFFFFull << 48;
        mlut[t] = m;
    }

    // Q B-frags: row = qa+l32, k-chunk s*16 + hw*8 (scaled 0.125*log2e at proj)
    short8 qh[4];
    #pragma unroll
    for (int s = 0; s < 4; ++s)
        qh[s] = *(const short8*)(Qhi + ((size_t)bh * NSEQ + qa + l32) * HDIM + s * 16 + hw * 8);
    const unsigned long long* mrow = Mb + (qa + l32);

    short8 onesf;
    #pragma unroll
    for (int i = 0; i < 8; ++i) onesf[i] = (short)0x3F80;   // bf16 1.0

    f32x16 O0, O1, Ol;
    #pragma unroll
    for (int i = 0; i < 16; ++i) { O0[i] = 0.f; O1[i] = 0.f; Ol[i] = 0.f; }

    const unsigned short* gk = Khi + (size_t)bh * NSEQ * HDIM;
    const unsigned short* gv = Vt  + (size_t)bh * HDIM * NSEQ;

    const int ci0 = t, ci1 = t + 256;
    const int sr0 = ci0 >> 3, sc0 = (ci0 & 7) * 8;
    const int sr1 = ci1 >> 3, sc1 = (ci1 & 7) * 8;

    const int ktBeg = ks * ktSpan, ktEnd = ktBeg + ktSpan;

    // ---- prologue: stage first K/V tile ----
    {
        const int k0 = ktBeg * 64;
        uint4 ka = *(const uint4*)(gk + (size_t)(k0 + sr0) * HDIM + sc0);
        uint4 kc = *(const uint4*)(gk + (size_t)(k0 + sr1) * HDIM + sc1);
        uint4 va = *(const uint4*)(gv + (size_t)sr0 * NSEQ + k0 + sc0);
        uint4 vc = *(const uint4*)(gv + (size_t)sr1 * NSEQ + k0 + sc1);
        *(uint4*)&KS[sr0 * STR + sc0] = ka;
        *(uint4*)&KS[sr1 * STR + sc1] = kc;
        *(uint4*)&VS[sr0 * STR + sc0] = va;
        *(uint4*)&VS[sr1 * STR + sc1] = vc;
    }
    __syncthreads();   // fences both staging and mlut init

    for (int kt = ktBeg; kt < ktEnd; ++kt) {
        const unsigned short* ksrc = KS;
        const unsigned short* vsrc = VS;
        const unsigned long long mw = mrow[(size_t)kt * NSEQ];

        // ---- S^T = K Q^T per 32-key tile; exp2; in-register redistribute ----
        short8 pf[4];
        #pragma unroll
        for (int nt = 0; nt < 2; ++nt) {
            f32x16 S;
            #pragma unroll
            for (int i = 0; i < 16; ++i) S[i] = 0.f;
            __builtin_amdgcn_s_setprio(1);
            #pragma unroll
            for (int s = 0; s < 4; ++s) {
                short8 kb = *(const short8*)&ksrc[(nt * 32 + l32) * STR + s * 16 + hw * 8];
                S = MFMA32(kb, qh[s], S, 0, 0, 0);   // swapped: lane l32 = q col
            }
            __builtin_amdgcn_s_setprio(0);
            // lane (l32,hw): p[r] = P[q=qa+l32][key = nt*32 + (r&3)+8*(r>>2)+4*hw]
            float p[16];
            #pragma unroll
            for (int r = 0; r < 16; ++r) p[r] = EXP2F(S[r]);
            unsigned w[8];
            #pragma unroll
            for (int i = 0; i < 8; ++i) w[i] = cvtpk(p[2 * i], p[2 * i + 1]);
            // exchange half-wave partners: one swap fills two fragment words
            pswap(w[0], w[2]); pswap(w[1], w[3]);
            pswap(w[4], w[6]); pswap(w[5], w[7]);
            union { short8 s8; unsigned u[4]; } A, B2;
            A.u[0] = w[0]; A.u[1] = w[1]; A.u[2] = w[2]; A.u[3] = w[3];
            B2.u[0] = w[4]; B2.u[1] = w[5]; B2.u[2] = w[6]; B2.u[3] = w[7];
            pf[2 * nt]     = A.s8;    // keys nt*32 + hw*8 + 0..7 (per 16-chunk)
            pf[2 * nt + 1] = B2.s8;
        }

        // ---- issue next-tile global loads (latency hides under mask+PV) ----
        uint4 nk0, nk1, nv0, nv1;
        const bool more = (kt + 1 < ktEnd);
        if (more) {
            const int k0n = (kt + 1) * 64;
            nk0 = *(const uint4*)(gk + (size_t)(k0n + sr0) * HDIM + sc0);
            nk1 = *(const uint4*)(gk + (size_t)(k0n + sr1) * HDIM + sc1);
            nv0 = *(const uint4*)(gv + (size_t)sr0 * NSEQ + k0n + sc0);
            nv1 = *(const uint4*)(gv + (size_t)sr1 * NSEQ + k0n + sc1);
        }

        // ---- apply adjacency mask via LDS nibble LUT ----
        #pragma unroll
        for (int s = 0; s < 4; ++s) {
            const unsigned bits8 = (unsigned)(mw >> (s * 16 + hw * 8)) & 0xFFu;
            const unsigned long long lo = mlut[bits8 & 15u];
            const unsigned long long hi = mlut[bits8 >> 4];
            union { short8 s8; uint4 u; } x; x.s8 = pf[s];
            x.u.x &= (unsigned)lo; x.u.y &= (unsigned)(lo >> 32);
            x.u.z &= (unsigned)hi; x.u.w &= (unsigned)(hi >> 32);
            pf[s] = x.s8;
        }

        // ---- O += P @ V ; l += P @ ones ----
        __builtin_amdgcn_s_setprio(1);
        #pragma unroll
        for (int s = 0; s < 4; ++s) {
            short8 v0 = *(const short8*)&vsrc[(l32) * STR + s * 16 + hw * 8];
            short8 v1 = *(const short8*)&vsrc[(32 + l32) * STR + s * 16 + hw * 8];
            O0 = MFMA32(pf[s], v0, O0, 0, 0, 0);
            O1 = MFMA32(pf[s], v1, O1, 0, 0, 0);
            Ol = MFMA32(pf[s], onesf, Ol, 0, 0, 0);
        }
        __builtin_amdgcn_s_setprio(0);

        // ---- barrier 1: all waves done READING KS/VS for this tile ----
        __syncthreads();
        // ---- write staged regs into the (single) buffer ----
        if (more) {
            *(uint4*)&KS[sr0 * STR + sc0] = nk0;
            *(uint4*)&KS[sr1 * STR + sc1] = nk1;
            *(uint4*)&VS[sr0 * STR + sc0] = nv0;
            *(uint4*)&VS[sr1 * STR + sc1] = nv1;
        }
        // ---- barrier 2: writes visible for next iteration ----
        __syncthreads();
    }

    // ---- write bf16 O-partials (no normalization; merge kernel sums) ----
    const size_t obase = ((size_t)(ks * NB + b) * NH + h) * NSEQ;
    #pragma unroll
    for (int r = 0; r < 16; ++r) {
        const int qrow = qa + (r & 3) + 8 * (r >> 2) + 4 * hw;
        unsigned short* orow = Opart + (obase + qrow) * HDIM;
        orow[l32]      = f2bf(O0[r]);
        orow[32 + l32] = f2bf(O1[r]);
        if (l32 == 0) lpart[obase + qrow] = Ol[r];
    }
}

// ---------------------------------------------------------------------------
// Merge: ctx = (sum_i O_i) / (sum_i l_i), bf16 partials -> chi [B,N,D]
// ---------------------------------------------------------------------------
__global__ __launch_bounds__(256) void merge_kernel(
    const unsigned short* __restrict__ Opart, const float* __restrict__ lpart,
    unsigned short* __restrict__ chi, const int split)
{
    const int g = blockIdx.x * 256 + threadIdx.x;   // 262144 threads
    const int qitem = g >> 2;                       // (b*NH+h)*NSEQ+n
    const int grp = g & 3;                          // 16-dim group
    const size_t QS = (size_t)NB * NH * NSEQ;
    const size_t HS = QS * HDIM;

    float lsum = 0.f;
    for (int i = 0; i < split; ++i) lsum += lpart[qitem + (size_t)i * QS];
    const float inv = 1.0f / lsum;

    float acc[16];
    #pragma unroll
    for (int j = 0; j < 16; ++j) acc[j] = 0.f;
    const unsigned short* pa = Opart + (size_t)qitem * HDIM + grp * 16;
    for (int i = 0; i < split; ++i) {
        const unsigned short* p = pa + (size_t)i * HS;
        uint4 v0 = *(const uint4*)(p);
        uint4 v1 = *(const uint4*)(p + 8);
        const unsigned wv[8] = {v0.x, v0.y, v0.z, v0.w, v1.x, v1.y, v1.z, v1.w};
        #pragma unroll
        for (int j = 0; j < 8; ++j) {
            union { unsigned u; float f; } lo, hi;
            lo.u = wv[j] << 16;
            hi.u = wv[j] & 0xFFFF0000u;
            acc[2 * j]     += lo.f;
            acc[2 * j + 1] += hi.f;
        }
    }

    const int n = qitem & 2047, h = (qitem >> 11) & 7, b = qitem >> 14;
    unsigned short* dst = chi + ((size_t)b * NSEQ + n) * DMODEL + h * HDIM + grp * 16;

    unsigned short o[16];
    #pragma unroll
    for (int j = 0; j < 16; ++j) o[j] = f2bf(acc[j] * inv);
    uint4 u0, u1;
    u0.x = (unsigned)o[0]  | ((unsigned)o[1]  << 16);
    u0.y = (unsigned)o[2]  | ((unsigned)o[3]  << 16);
    u0.z = (unsigned)o[4]  | ((unsigned)o[5]  << 16);
    u0.w = (unsigned)o[6]  | ((unsigned)o[7]  << 16);
    u1.x = (unsigned)o[8]  | ((unsigned)o[9]  << 16);
    u1.y = (unsigned)o[10] | ((unsigned)o[11] << 16);
    u1.z = (unsigned)o[12] | ((unsigned)o[13] << 16);
    u1.w = (unsigned)o[14] | ((unsigned)o[15] << 16);
    *(uint4*)dst = u0;
    *(uint4*)(dst + 8) = u1;
}

// ---------------------------------------------------------------------------
extern "C" void kernel_launch(void* const* d_in, const int* in_sizes, int n_in,
                              void* d_out, int out_size, void* d_ws, size_t ws_size,
                              hipStream_t stream) {
    const float* x   = (const float*)d_in[0];
    const float* adj = (const float*)d_in[1];
    const float* Wq  = (const float*)d_in[2];
    const float* bq  = (const float*)d_in[3];
    const float* Wk  = (const float*)d_in[4];
    const float* bk  = (const float*)d_in[5];
    const float* Wv  = (const float*)d_in[6];
    const float* bv  = (const float*)d_in[7];
    const float* Wo  = (const float*)d_in[8];
    const float* bo  = (const float*)d_in[9];
    float* out = (float*)d_out;

    const size_t elems = (size_t)NB * NSEQ * DMODEL;   // 4,194,304
    unsigned short* Qhi  = (unsigned short*)d_ws;                    // 8.4 MB
    unsigned short* Khi  = Qhi + elems;                              // 8.4 MB
    unsigned short* Vt   = Khi + elems;                              // 8.4 MB
    unsigned long long* Mbits = (unsigned long long*)(Vt + elems);   // 512 KB
    unsigned short* xhi  = (unsigned short*)(Mbits + 32 * NSEQ);     // 8.4 MB
    unsigned short* Wthi = xhi + elems;                              // 2 MB
    unsigned short* Opart = Wthi + 4 * (size_t)DMODEL * DMODEL;      // bf16 partials
    // ctx (bf16) aliases xhi (dead after qkv_mfma_kernel)
    unsigned short* chi = xhi;

    // 4-way k-split if the workspace can hold 4 bf16 partials; else 2-way.
    const size_t QS = (size_t)NB * NH * NSEQ;          // 65536
    const size_t head = (size_t)((char*)Opart - (char*)d_ws);
    const size_t per_split = QS * HDIM * 2 + QS * 4;   // bf16 O + f32 l per split
    const int split  = (ws_size >= head + 4 * per_split) ? 4 : 2;
    const int sshift = (split == 4) ? 2 : 1;
    float* lpart = (float*)(Opart + (size_t)split * QS * HDIM);

    prep_kernel<<<dim3(7168), dim3(256), 0, stream>>>(
        adj, Mbits, x, xhi, Wq, Wk, Wv, Wo, Wthi);
    qkv_mfma_kernel<<<dim3(64, 12), dim3(256), 0, stream>>>(
        xhi, Wthi, bq, bk, bv, Qhi, Khi, Vt);
    attn_kernel<<<dim3(NSEQ / 128, NH, NB * split), dim3(256), 0, stream>>>(
        Qhi, Khi, Vt, Mbits, Opart, lpart, split, sshift);
    merge_kernel<<<dim3(1024), dim3(256), 0, stream>>>(Opart, lpart, chi, split);
    out_mfma_kernel<<<dim3(64, 4), dim3(256), 0, stream>>>(
        chi, Wthi, bo, out);
}